// Round 4
// baseline (15349.559 us; speedup 1.0000x reference)
//
#include <hip/hip_runtime.h>

// All reference tensors are float32 (setup_inputs uses jnp.float32 throughout);
// captions are int32. Rounds 1-3 failed with NaN because inputs were read as
// bf16 — fp32 low halves decode to NaN ~0.4% of the time. This round: fp32
// everywhere, simplest-possible kernels (no MFMA) to lock down the interface.

static __device__ __forceinline__ float my_tanh(float x) {
    x = fminf(fmaxf(x, -15.f), 15.f);
    float e = __expf(2.f * x);
    return (e - 1.f) / (e + 1.f);
}
static __device__ __forceinline__ float my_sigmoid(float x) {
    return 1.f / (1.f + __expf(-x));
}

// ---------------------------------------------------------------------------
// Tiled fp32 transpose: out[c*R + r] = in[r*ld_in + c]
// ---------------------------------------------------------------------------
__global__ __launch_bounds__(256) void transpose_f32(
    const float* __restrict__ in, float* __restrict__ out,
    int R, int C, int ld_in)
{
    __shared__ float tile[32][33];
    int tc = blockIdx.x * 32;
    int tr = blockIdx.y * 32;
    int tx = threadIdx.x & 31, ty = threadIdx.x >> 5;  // 32 x 8
    #pragma unroll
    for (int i = 0; i < 4; i++) {
        int r = tr + ty + i * 8, c = tc + tx;
        tile[ty + i * 8][tx] = (r < R && c < C) ? in[(long)r * ld_in + c] : 0.f;
    }
    __syncthreads();
    #pragma unroll
    for (int i = 0; i < 4; i++) {
        int c = tc + ty + i * 8, r = tr + tx;
        if (c < C && r < R) out[(long)c * R + r] = tile[tx][ty + i * 8];
    }
}

// ---------------------------------------------------------------------------
// Simple fp32 GEMM: C[m0..m0+16, n] = A[M,K] @ B[K,N] + bias.
// Thread per output column, 16 rows per block, A-tile staged in LDS (32 KB).
// Requires M%16==0, K%512==0; N-edge masked.
// ---------------------------------------------------------------------------
__global__ __launch_bounds__(256) void gemm_f32(
    const float* __restrict__ A, int lda,
    const float* __restrict__ B, int ldb,
    const float* __restrict__ bias,
    float* __restrict__ C, int ldc,
    int M, int N, int K)
{
    __shared__ float Asm[16 * 512];
    const int tid = threadIdx.x;
    const int n = blockIdx.x * 256 + tid;
    const bool active = n < N;
    const int nn = active ? n : (N - 1);
    const int m0 = blockIdx.y * 16;

    float acc[16];
    #pragma unroll
    for (int i = 0; i < 16; i++) acc[i] = 0.f;

    for (int kt = 0; kt < K; kt += 512) {
        for (int idx = tid; idx < 16 * 512; idx += 256) {
            int i = idx >> 9, kk = idx & 511;
            Asm[idx] = A[(long)(m0 + i) * lda + kt + kk];
        }
        __syncthreads();
        for (int k0 = 0; k0 < 512; k0 += 4) {
            float4 a4[16];
            #pragma unroll
            for (int i = 0; i < 16; i++)
                a4[i] = *(const float4*)(&Asm[i * 512 + k0]);
            #pragma unroll
            for (int j = 0; j < 4; j++) {
                float bv = B[(long)(kt + k0 + j) * ldb + nn];
                #pragma unroll
                for (int i = 0; i < 16; i++) {
                    float av = (j == 0) ? a4[i].x : (j == 1) ? a4[i].y
                             : (j == 2) ? a4[i].z : a4[i].w;
                    acc[i] = fmaf(av, bv, acc[i]);
                }
            }
        }
        __syncthreads();
    }

    if (active) {
        float bb = bias ? bias[n] : 0.f;
        #pragma unroll
        for (int i = 0; i < 16; i++)
            C[(long)(m0 + i) * ldc + n] = acc[i] + bb;
    }
}

// ---------------------------------------------------------------------------
// Sequential scan, fp32 VALU, 16 blocks x 4 batch elements, 256 threads.
// Weights in k-major layouts so gate reads coalesce along the output index;
// each weight value loaded once per block serves 4 batch elements.
// LDS: 78.8 KB/block.
// ---------------------------------------------------------------------------
__global__ __launch_bounds__(256) void scan_f32(
    const float* __restrict__ enc,      // [64,49,512]
    const float* __restrict__ att1,     // [64,49,256]
    const int*  __restrict__ captions,  // [64,50]
    const float* __restrict__ emb,      // [10000,512]
    const float* __restrict__ W_da,     // [512,256]  natural [k][j]
    const float* __restrict__ b_da,     // [256]
    const float* __restrict__ W_fa,     // [256]
    const float* __restrict__ b_fa,     // [1]
    const float* __restrict__ Wt_ih,    // [1024,1536]  (W_ih transposed)
    const float* __restrict__ Wt_hh,    // [512,1536]   (W_hh transposed)
    const float* __restrict__ b_ih,     // [1536]
    const float* __restrict__ b_hh,     // [1536]
    float* __restrict__ Hbuf)           // [3200,512]  (row m = b*50+t)
{
    __shared__ float h[4 * 512], xr[4 * 512], cx[4 * 512];
    __shared__ float att2[4 * 256];
    __shared__ float alpha[4 * 64];
    __shared__ float gi[4 * 1536], gh[4 * 1536];

    const int tid = threadIdx.x;
    const int bb0 = blockIdx.x * 4;

    for (int i = tid; i < 4 * 512; i += 256) h[i] = 0.f;
    __syncthreads();

    for (int t = 0; t < 50; t++) {
        // ---- (a) embedding rows for this step (4 batches)
        for (int i = tid; i < 4 * 512; i += 256) {
            int b = i >> 9, d = i & 511;
            int cap = captions[(bb0 + b) * 50 + t];
            xr[i] = emb[(long)cap * 512 + d];
        }
        // ---- (b) att2[b][j] = sum_k h[b][k] * W_da[k][j] + b_da[j]  (j = tid)
        {
            float a0 = 0.f, a1 = 0.f, a2 = 0.f, a3 = 0.f;
            for (int k = 0; k < 512; k++) {
                float w = W_da[k * 256 + tid];
                a0 = fmaf(h[k], w, a0);
                a1 = fmaf(h[512 + k], w, a1);
                a2 = fmaf(h[1024 + k], w, a2);
                a3 = fmaf(h[1536 + k], w, a3);
            }
            float bd = b_da[tid];
            att2[tid] = a0 + bd;
            att2[256 + tid] = a1 + bd;
            att2[512 + tid] = a2 + bd;
            att2[768 + tid] = a3 + bd;
        }
        __syncthreads();
        // ---- (c) scores: thread per (b,l), 196 tasks
        if (tid < 196) {
            int b = tid / 49, l = tid - b * 49;
            const float* ar = att1 + ((long)(bb0 + b) * 49 + l) * 256;
            float s = 0.f;
            for (int j = 0; j < 256; j++)
                s += my_tanh(ar[j] + att2[b * 256 + j]) * W_fa[j];
            alpha[b * 64 + l] = s + b_fa[0];
        }
        __syncthreads();
        // ---- (d) softmax over L=49 (thread per b)
        if (tid < 4) {
            float* al = alpha + tid * 64;
            float m = al[0];
            for (int l = 1; l < 49; l++) m = fmaxf(m, al[l]);
            float su = 0.f;
            for (int l = 0; l < 49; l++) { al[l] = __expf(al[l] - m); su += al[l]; }
            float inv = 1.f / su;
            for (int l = 0; l < 49; l++) al[l] *= inv;
        }
        __syncthreads();
        // ---- (e) context[b][d] = sum_l alpha[b][l] * enc[b,l,d]
        for (int i = tid; i < 4 * 512; i += 256) {
            int b = i >> 9, d = i & 511;
            const float* e0 = enc + ((long)(bb0 + b) * 49) * 512 + d;
            float c = 0.f;
            for (int l = 0; l < 49; l++)
                c = fmaf(alpha[b * 64 + l], e0[l * 512], c);
            cx[i] = c;
        }
        __syncthreads();
        // ---- (f) gates: n = tid + c*256 (c<6); each weight load serves 4 batches
        {
            float ai[6][4], ah[6][4];
            #pragma unroll
            for (int c = 0; c < 6; c++)
                #pragma unroll
                for (int b = 0; b < 4; b++) { ai[c][b] = 0.f; ah[c][b] = 0.f; }
            for (int k = 0; k < 512; k++) {
                float xk0 = xr[k],        xk1 = xr[512 + k],
                      xk2 = xr[1024 + k], xk3 = xr[1536 + k];
                float ck0 = cx[k],        ck1 = cx[512 + k],
                      ck2 = cx[1024 + k], ck3 = cx[1536 + k];
                float hk0 = h[k],         hk1 = h[512 + k],
                      hk2 = h[1024 + k],  hk3 = h[1536 + k];
                const float* wx = Wt_ih + (long)k * 1536;
                const float* wc = Wt_ih + (long)(k + 512) * 1536;
                const float* wh = Wt_hh + (long)k * 1536;
                #pragma unroll
                for (int c = 0; c < 6; c++) {
                    int nx = tid + c * 256;
                    float wxv = wx[nx], wcv = wc[nx], whv = wh[nx];
                    ai[c][0] = fmaf(xk0, wxv, ai[c][0]);
                    ai[c][1] = fmaf(xk1, wxv, ai[c][1]);
                    ai[c][2] = fmaf(xk2, wxv, ai[c][2]);
                    ai[c][3] = fmaf(xk3, wxv, ai[c][3]);
                    ai[c][0] = fmaf(ck0, wcv, ai[c][0]);
                    ai[c][1] = fmaf(ck1, wcv, ai[c][1]);
                    ai[c][2] = fmaf(ck2, wcv, ai[c][2]);
                    ai[c][3] = fmaf(ck3, wcv, ai[c][3]);
                    ah[c][0] = fmaf(hk0, whv, ah[c][0]);
                    ah[c][1] = fmaf(hk1, whv, ah[c][1]);
                    ah[c][2] = fmaf(hk2, whv, ah[c][2]);
                    ah[c][3] = fmaf(hk3, whv, ah[c][3]);
                }
            }
            #pragma unroll
            for (int c = 0; c < 6; c++) {
                int nx = tid + c * 256;
                float bi = b_ih[nx], bh = b_hh[nx];
                #pragma unroll
                for (int b = 0; b < 4; b++) {
                    gi[b * 1536 + nx] = ai[c][b] + bi;
                    gh[b * 1536 + nx] = ah[c][b] + bh;
                }
            }
        }
        __syncthreads();
        // ---- (g) GRU combine + h update (jj = tid, tid+256 per batch)
        #pragma unroll
        for (int c = 0; c < 2; c++) {
            int jj = tid + c * 256;
            #pragma unroll
            for (int b = 0; b < 4; b++) {
                float r  = my_sigmoid(gi[b * 1536 + jj] + gh[b * 1536 + jj]);
                float z  = my_sigmoid(gi[b * 1536 + jj + 512] + gh[b * 1536 + jj + 512]);
                float nn = my_tanh(gi[b * 1536 + jj + 1024] + r * gh[b * 1536 + jj + 1024]);
                float hnew = (1.f - z) * nn + z * h[b * 512 + jj];
                h[b * 512 + jj] = hnew;
                Hbuf[(((long)(bb0 + b)) * 50 + t) * 512 + jj] = hnew;
            }
        }
        __syncthreads();
    }
}

// ---------------------------------------------------------------------------
extern "C" void kernel_launch(void* const* d_in, const int* in_sizes, int n_in,
                              void* d_out, int out_size, void* d_ws, size_t ws_size,
                              hipStream_t stream) {
    const float* spatial = (const float*)d_in[0];
    const int*   captions= (const int*)d_in[1];
    const float* W_feat  = (const float*)d_in[2];
    const float* b_feat  = (const float*)d_in[3];
    const float* W_ea    = (const float*)d_in[4];
    const float* b_ea    = (const float*)d_in[5];
    const float* W_da    = (const float*)d_in[6];
    const float* b_da    = (const float*)d_in[7];
    const float* W_fa    = (const float*)d_in[8];
    const float* b_fa    = (const float*)d_in[9];
    const float* emb     = (const float*)d_in[10];
    const float* W_ih    = (const float*)d_in[11];
    const float* W_hh    = (const float*)d_in[12];
    const float* b_ih    = (const float*)d_in[13];
    const float* b_hh    = (const float*)d_in[14];
    const float* W_fc    = (const float*)d_in[15];
    const float* b_fc    = (const float*)d_in[16];
    float* out = (float*)d_out;

    // Workspace: 25.6 MB fp32. Guard -> finite 0.153 signature if too small.
    char* ws = (char*)d_ws;
    float* Wt_ih = (float*)ws; ws += (size_t)1024 * 1536 * 4;   //  6,291,456
    float* Wt_hh = (float*)ws; ws += (size_t)512 * 1536 * 4;    //  3,145,728
    float* enc   = (float*)ws; ws += (size_t)3136 * 512 * 4;    //  6,422,528
    float* att1  = (float*)ws; ws += (size_t)3136 * 256 * 4;    //  3,211,264
    float* Hbuf  = (float*)ws; ws += (size_t)3200 * 512 * 4;    //  6,553,600
    const size_t NEED = 6291456ull + 3145728 + 6422528 + 3211264 + 6553600;
    if (ws_size < NEED) return;

    dim3 blk(256);
    // Wt_ih[1024,1536] = W_ih[1536,1024]^T ; Wt_hh[512,1536] = W_hh[1536,512]^T
    transpose_f32<<<dim3(32, 48), blk, 0, stream>>>(W_ih, Wt_ih, 1536, 1024, 1024);
    transpose_f32<<<dim3(16, 48), blk, 0, stream>>>(W_hh, Wt_hh, 1536, 512, 512);

    // enc = spatial @ W_feat + b_feat          [3136,512]
    gemm_f32<<<dim3(2, 196), blk, 0, stream>>>(spatial, 2048, W_feat, 512, b_feat,
                                               enc, 512, 3136, 512, 2048);
    // att1 = enc @ W_ea + b_ea                 [3136,256]
    gemm_f32<<<dim3(1, 196), blk, 0, stream>>>(enc, 512, W_ea, 256, b_ea,
                                               att1, 256, 3136, 256, 512);
    // recurrent scan -> Hbuf                   [3200,512]
    scan_f32<<<dim3(16), blk, 0, stream>>>(enc, att1, captions, emb,
                                           W_da, b_da, W_fa, b_fa,
                                           Wt_ih, Wt_hh, b_ih, b_hh, Hbuf);
    // logits = Hbuf @ W_fc + b_fc -> d_out     [3200,10000]
    gemm_f32<<<dim3(40, 200), blk, 0, stream>>>(Hbuf, 512, W_fc, 10000, b_fc,
                                                out, 10000, 3200, 10000, 512);
}